// Round 1
// baseline (415.700 us; speedup 1.0000x reference)
//
#include <hip/hip_runtime.h>

#define IMG_H 256
#define IMG_W 256
#define KS 33
#define PAD 16
#define THRESH 1e-4f
#define FH_PER 3                    // 33 fh values -> 11 chunks of 3
#define NCHUNK 11
#define ROWS 4                      // image rows per block (1 per wave)
#define RSTG (ROWS + FH_PER - 1)    // staged padded rows = 6
#define LW (IMG_W + 2 * PAD)        // padded row width = 288
#define PLANE (IMG_H * IMG_W)       // 65536

__device__ __forceinline__ float f4c(const float4 v, int i) {
    return i == 0 ? v.x : i == 1 ? v.y : i == 2 ? v.z : v.w;
}

// Block = 256 threads = 4 waves; each wave owns one image row, each lane owns
// 4 consecutive pixels (x0 = 4*lane). grid = (64 row-groups, 11 fh-chunks).
// Kernels are read as float4 (all 4 pixels' weights for one tap in one load,
// 1 KB per wave-load). Image rows are staged clamped+padded in LDS once and
// consumed via 16B-aligned float4 sliding windows (1 ds_read_b128 per channel
// per 4 taps). Each chunk atomically accumulates into d_out (zeroed first).
__global__ __launch_bounds__(256, 4)
void reblur_kernel(const float* __restrict__ img,
                   const float* __restrict__ ker,
                   float* __restrict__ out)
{
    const int tid   = threadIdx.x;
    const int wvid  = tid >> 6;          // 0..3: row within block
    const int lane  = tid & 63;
    const int ybase = blockIdx.x * ROWS;
    const int y     = ybase + wvid;
    const int fh0   = blockIdx.y * FH_PER;
    const int x0    = lane * 4;

    __shared__ __align__(16) float simg[3][RSTG][LW];

    // Stage padded rows: simg[c][r][px] = img[c][clamp(ybase+fh0+r-16)][clamp(px-16)]
    const int tot = 3 * RSTG * LW;       // 5184
    for (int i = tid; i < tot; i += 256) {
        const int c  = i / (RSTG * LW);
        const int rm = i - c * (RSTG * LW);
        const int r  = rm / LW;
        const int px = rm - r * LW;
        int yy = ybase + fh0 + r - PAD;
        yy = yy < 0 ? 0 : (yy > IMG_H - 1 ? IMG_H - 1 : yy);
        int xx = px - PAD;
        xx = xx < 0 ? 0 : (xx > IMG_W - 1 ? IMG_W - 1 : xx);
        simg[c][r][px] = img[c * PLANE + yy * IMG_W + xx];
    }
    __syncthreads();

    float acc[3][4] = {};

    // float4 view of Kernels: tap k, row y, lane -> K[k][y][4*lane .. 4*lane+3]
    const float4* kb = reinterpret_cast<const float4*>(ker)
                     + (size_t)fh0 * KS * (PLANE / 4) + y * (IMG_W / 4) + lane;

    #pragma unroll
    for (int dfh = 0; dfh < FH_PER; ++dfh) {
        const int r = wvid + dfh;        // padded-row index for this wave's fh
        const float4* s0 = reinterpret_cast<const float4*>(&simg[0][r][x0]);
        const float4* s1 = reinterpret_cast<const float4*>(&simg[1][r][x0]);
        const float4* s2 = reinterpret_cast<const float4*>(&simg[2][r][x0]);
        const float4* kf = kb + (size_t)(dfh * KS) * (PLANE / 4);

        float4 a0 = s0[0], a1 = s1[0], a2 = s2[0];

        #pragma unroll
        for (int g = 0; g < 8; ++g) {    // taps fw = 4g .. 4g+3
            const float4 b0 = s0[g + 1];
            const float4 b1 = s1[g + 1];
            const float4 b2 = s2[g + 1];
            #pragma unroll
            for (int j = 0; j < 4; ++j) {
                const float4 wt = kf[(size_t)(4 * g + j) * (PLANE / 4)];
                float4 th;
                th.x = wt.x > THRESH ? wt.x : 0.f;
                th.y = wt.y > THRESH ? wt.y : 0.f;
                th.z = wt.z > THRESH ? wt.z : 0.f;
                th.w = wt.w > THRESH ? wt.w : 0.f;
                #pragma unroll
                for (int p = 0; p < 4; ++p) {
                    const int e = j + p;             // window element, 0..6
                    const float v0 = e < 4 ? f4c(a0, e) : f4c(b0, e - 4);
                    const float v1 = e < 4 ? f4c(a1, e) : f4c(b1, e - 4);
                    const float v2 = e < 4 ? f4c(a2, e) : f4c(b2, e - 4);
                    const float w  = f4c(th, p);
                    acc[0][p] = fmaf(w, v0, acc[0][p]);
                    acc[1][p] = fmaf(w, v1, acc[1][p]);
                    acc[2][p] = fmaf(w, v2, acc[2][p]);
                }
            }
            a0 = b0; a1 = b1; a2 = b2;
        }

        // tail tap fw = 32: window is a* (== s*[8] = cols x0+32 .. x0+35)
        {
            const float4 wt = kf[(size_t)32 * (PLANE / 4)];
            float4 th;
            th.x = wt.x > THRESH ? wt.x : 0.f;
            th.y = wt.y > THRESH ? wt.y : 0.f;
            th.z = wt.z > THRESH ? wt.z : 0.f;
            th.w = wt.w > THRESH ? wt.w : 0.f;
            #pragma unroll
            for (int p = 0; p < 4; ++p) {
                const float w = f4c(th, p);
                acc[0][p] = fmaf(w, f4c(a0, p), acc[0][p]);
                acc[1][p] = fmaf(w, f4c(a1, p), acc[1][p]);
                acc[2][p] = fmaf(w, f4c(a2, p), acc[2][p]);
            }
        }
    }

    const int obase = y * IMG_W + x0;
    #pragma unroll
    for (int p = 0; p < 4; ++p) {
        atomicAdd(out + obase + p,             acc[0][p]);
        atomicAdd(out + PLANE + obase + p,     acc[1][p]);
        atomicAdd(out + 2 * PLANE + obase + p, acc[2][p]);
    }
}

extern "C" void kernel_launch(void* const* d_in, const int* in_sizes, int n_in,
                              void* d_out, int out_size, void* d_ws, size_t ws_size,
                              hipStream_t stream) {
    const float* img = (const float*)d_in[0];   // [1,3,256,256] fp32
    const float* ker = (const float*)d_in[1];   // [1,1089,256,256] fp32
    float* out = (float*)d_out;                 // [1,3,256,256] fp32

    // d_out is poisoned 0xAA before every timed launch — zero it ourselves.
    hipMemsetAsync(out, 0, (size_t)out_size * sizeof(float), stream);

    dim3 grid(IMG_H / ROWS, NCHUNK);            // (64, 11)
    reblur_kernel<<<grid, 256, 0, stream>>>(img, ker, out);
}